// Round 5
// baseline (1055.038 us; speedup 1.0000x reference)
//
#include <hip/hip_runtime.h>
#include <hip/hip_bf16.h>

typedef __bf16 bf16_t;
typedef __bf16 bf16x8 __attribute__((ext_vector_type(8)));
typedef __bf16 bf16x4 __attribute__((ext_vector_type(4)));
typedef float f32x4 __attribute__((ext_vector_type(4)));
typedef int i32x4 __attribute__((ext_vector_type(4)));

__device__ __forceinline__ f32x4 mfma16(bf16x8 a, bf16x8 b, f32x4 c) {
  return __builtin_amdgcn_mfma_f32_16x16x32_bf16(a, b, c, 0, 0, 0);
}

__device__ __forceinline__ void gload16(const void* g, void* l) {
  __builtin_amdgcn_global_load_lds(
      (const __attribute__((address_space(1))) void*)g,
      (__attribute__((address_space(3))) void*)l, 16, 0, 0);
}

// ---------------- ternary threshold: deterministic fp64 reduction (fused, 6 weights) --------
__global__ void abssum_all(const float* __restrict__ W0, const float* __restrict__ W1_,
                           const float* __restrict__ W2_, const float* __restrict__ W3,
                           const float* __restrict__ W4, const float* __restrict__ W5,
                           double* __restrict__ partial) {
  __shared__ double sd[256];
  const int w = blockIdx.y, tid = threadIdx.x;
  const float* W = (w == 0) ? W0 : (w == 1) ? W1_ : (w == 2) ? W2_ : (w == 3) ? W3 : (w == 4) ? W4 : W5;
  const int n4 = (w < 4) ? 1048576 : 4194304;
  double s = 0.0;
  for (int i = blockIdx.x * 256 + tid; i < n4; i += 262144) {
    float4 v = ((const float4*)W)[i];
    s += (double)fabsf(v.x); s += (double)fabsf(v.y);
    s += (double)fabsf(v.z); s += (double)fabsf(v.w);
  }
  sd[tid] = s; __syncthreads();
  for (int st = 128; st > 0; st >>= 1) { if (tid < st) sd[tid] += sd[tid + st]; __syncthreads(); }
  if (tid == 0) partial[w * 1024 + blockIdx.x] = sd[0];
}

__global__ void abssum_fin(const double* __restrict__ partial, double* __restrict__ sums) {
  __shared__ double sd[256];
  const int tid = threadIdx.x;
  const double* p = partial + blockIdx.x * 1024;
  double s = p[tid] + p[tid + 256] + p[tid + 512] + p[tid + 768];
  sd[tid] = s; __syncthreads();
  for (int st = 128; st > 0; st >>= 1) { if (tid < st) sd[tid] += sd[tid + st]; __syncthreads(); }
  if (tid == 0) sums[blockIdx.x] = sd[0];
}

__global__ void ternarize_k(const float* __restrict__ W, bf16_t* __restrict__ out,
                            const double* __restrict__ sum, double n) {
  const double thr = sum[0] / n;
  const int i = blockIdx.x * 256 + threadIdx.x;  // float4 index; grid sized exactly
  float4 v = ((const float4*)W)[i];
  bf16x4 o;
  float t;
  t = ((double)fabsf(v.x) > thr) ? (v.x > 0.f ? 1.f : -1.f) : 0.f; o[0] = (bf16_t)t;
  t = ((double)fabsf(v.y) > thr) ? (v.y > 0.f ? 1.f : -1.f) : 0.f; o[1] = (bf16_t)t;
  t = ((double)fabsf(v.z) > thr) ? (v.z > 0.f ? 1.f : -1.f) : 0.f; o[2] = (bf16_t)t;
  t = ((double)fabsf(v.w) > thr) ? (v.w > 0.f ? 1.f : -1.f) : 0.f; o[3] = (bf16_t)t;
  *(bf16x4*)&out[(size_t)i * 4] = o;
}

// ---------------- x -> hi/lo bf16 split ----------------
__global__ void split_x_k(const float* __restrict__ X, bf16_t* __restrict__ xh, bf16_t* __restrict__ xl) {
  const int i = blockIdx.x * 256 + threadIdx.x;  // float4 index
  float4 v = ((const float4*)X)[i];
  bf16x4 h, l;
  h[0] = (bf16_t)v.x; l[0] = (bf16_t)(v.x - (float)h[0]);
  h[1] = (bf16_t)v.y; l[1] = (bf16_t)(v.y - (float)h[1]);
  h[2] = (bf16_t)v.z; l[2] = (bf16_t)(v.z - (float)h[2]);
  h[3] = (bf16_t)v.w; l[3] = (bf16_t)(v.w - (float)h[3]);
  *(bf16x4*)&xh[(size_t)i * 4] = h;
  *(bf16x4*)&xl[(size_t)i * 4] = l;
}

// ---------------- GEMM v2 (8-wave, BM=128 x BN=256, BK=64) ----------------
// C[t][o] = sum_k A[t][k] * W[o][k]  (W ternary bf16 [N][K] row-major).
// XOR-swizzled LDS (unit ^= row&7): pre-swizzled global src for global_load_lds,
// swizzled ds_read_b128 -> 2 lanes/bank (conflict-free). Phase-split MFMA with
// s_setprio. Counted vmcnt, never 0 in-loop. Non-split: 3-buffer depth-2
// prefetch vmcnt(12); SPLITA: 2-buffer depth-1 vmcnt(8) (2x compute/tile).
// EPI: 0 = split-store (C0 hi, C1 lo), 1 = vT transposed store, 2 = f32, 3 = relu bf16
template <int EPI, bool SPLITA>
__global__ __launch_bounds__(512, 2) void gemm8(
    const bf16_t* __restrict__ Ah, const bf16_t* __restrict__ Al,
    const bf16_t* __restrict__ Bw,
    void* __restrict__ C0, void* __restrict__ C1,
    int M, int N, int K) {
  constexpr int NBUF = SPLITA ? 2 : 3;
  __shared__ __align__(16) bf16_t sA[NBUF][128 * 64];
  __shared__ __align__(16) bf16_t sA2[SPLITA ? 2 : 1][SPLITA ? 128 * 64 : 8];
  __shared__ __align__(16) bf16_t sB[NBUF][256 * 64];

  const int tid = threadIdx.x;
  const int wid = tid >> 6, lane = tid & 63, lr = lane & 15, lg = lane >> 4;
  const int wr = wid >> 2, wc = wid & 3;     // wave grid 2M x 4N, per-wave 64x64
  const size_t Ks = (size_t)K;
  const size_t m0 = (size_t)blockIdx.y * 128, n0 = (size_t)blockIdx.x * 256;
  const int nt = K / 64;

  f32x4 acc[4][4] = {};

  // stage K-tile kt into buffer bi. LDS linear in (round,tid); global col-unit
  // pre-swizzled: slot s holds global unit s^(row&7).
  auto STAGE = [&](int bi, int kt) {
    const size_t ko = (size_t)kt * 64;
#pragma unroll
    for (int i = 0; i < 2; i++) {                       // A: 128 rows
      const int g = i * 512 + tid;
      const int r = g >> 3;
      const int su = (tid & 7) ^ (r & 7);
      const int lo = (i * 512 + wid * 64) * 8;          // wave-uniform LDS base
      gload16(Ah + (m0 + r) * Ks + ko + su * 8, (void*)&sA[bi][lo]);
      if constexpr (SPLITA) gload16(Al + (m0 + r) * Ks + ko + su * 8, (void*)&sA2[bi][lo]);
    }
#pragma unroll
    for (int i = 0; i < 4; i++) {                       // B: 256 rows
      const int g = i * 512 + tid;
      const int r = g >> 3;
      const int su = (tid & 7) ^ (r & 7);
      gload16(Bw + (n0 + r) * Ks + ko + su * 8, (void*)&sB[bi][(i * 512 + wid * 64) * 8]);
    }
  };
  // fragment reads (row&7 == lr&7 since 16|frag-row-offset)
  auto LDA = [&](const bf16_t* base, int m, int k) -> bf16x8 {
    const int row = wr * 64 + m * 16 + lr;
    const int u = (k * 4 + lg) ^ (lr & 7);
    return *(const bf16x8*)&base[row * 64 + u * 8];
  };
  auto LDB = [&](const bf16_t* base, int n, int k) -> bf16x8 {
    const int row = wc * 64 + n * 16 + lr;
    const int u = (k * 4 + lg) ^ (lr & 7);
    return *(const bf16x8*)&base[row * 64 + u * 8];
  };

  STAGE(0, 0);
  if constexpr (!SPLITA) { if (nt > 1) STAGE(1, 1); }
  int bc = 0;  // compute buffer for tile kt
  for (int kt = 0; kt < nt; kt++) {
    if constexpr (SPLITA) {
      if (kt + 1 < nt) {
        STAGE(bc ^ 1, kt + 1);
        asm volatile("s_waitcnt vmcnt(8)" ::: "memory");
      } else {
        asm volatile("s_waitcnt vmcnt(0)" ::: "memory");
      }
    } else {
      if (kt + 2 < nt) {
        const int bs = bc ? bc - 1 : 2;     // (bc+2)%3
        STAGE(bs, kt + 2);
        asm volatile("s_waitcnt vmcnt(12)" ::: "memory");
      } else if (kt + 1 < nt) {
        asm volatile("s_waitcnt vmcnt(6)" ::: "memory");
      } else {
        asm volatile("s_waitcnt vmcnt(0)" ::: "memory");
      }
    }
    __builtin_amdgcn_s_barrier();   // tile kt visible to all waves

    bf16x8 a[4][2], b2[2][2];
#pragma unroll
    for (int m = 0; m < 4; m++)
#pragma unroll
      for (int k = 0; k < 2; k++) a[m][k] = LDA(&sA[bc][0], m, k);
    // phase 1: n = 0,1
#pragma unroll
    for (int n = 0; n < 2; n++)
#pragma unroll
      for (int k = 0; k < 2; k++) b2[n][k] = LDB(&sB[bc][0], n, k);
    __builtin_amdgcn_s_setprio(1);
#pragma unroll
    for (int k = 0; k < 2; k++)
#pragma unroll
      for (int m = 0; m < 4; m++)
#pragma unroll
        for (int n = 0; n < 2; n++) acc[m][n] = mfma16(a[m][k], b2[n][k], acc[m][n]);
    __builtin_amdgcn_s_setprio(0);
    // phase 2: n = 2,3
#pragma unroll
    for (int n = 0; n < 2; n++)
#pragma unroll
      for (int k = 0; k < 2; k++) b2[n][k] = LDB(&sB[bc][0], n + 2, k);
    __builtin_amdgcn_s_setprio(1);
#pragma unroll
    for (int k = 0; k < 2; k++)
#pragma unroll
      for (int m = 0; m < 4; m++)
#pragma unroll
        for (int n = 0; n < 2; n++) acc[m][n + 2] = mfma16(a[m][k], b2[n][k], acc[m][n + 2]);
    __builtin_amdgcn_s_setprio(0);
    if constexpr (SPLITA) {
      // phase 3: A-lo, n = 2,3 (b2 still holds n=2,3)
#pragma unroll
      for (int m = 0; m < 4; m++)
#pragma unroll
        for (int k = 0; k < 2; k++) a[m][k] = LDA(&sA2[bc][0], m, k);
      __builtin_amdgcn_s_setprio(1);
#pragma unroll
      for (int k = 0; k < 2; k++)
#pragma unroll
        for (int m = 0; m < 4; m++)
#pragma unroll
          for (int n = 0; n < 2; n++) acc[m][n + 2] = mfma16(a[m][k], b2[n][k], acc[m][n + 2]);
      __builtin_amdgcn_s_setprio(0);
      // phase 4: A-lo, n = 0,1
#pragma unroll
      for (int n = 0; n < 2; n++)
#pragma unroll
        for (int k = 0; k < 2; k++) b2[n][k] = LDB(&sB[bc][0], n, k);
      __builtin_amdgcn_s_setprio(1);
#pragma unroll
      for (int k = 0; k < 2; k++)
#pragma unroll
        for (int m = 0; m < 4; m++)
#pragma unroll
          for (int n = 0; n < 2; n++) acc[m][n] = mfma16(a[m][k], b2[n][k], acc[m][n]);
      __builtin_amdgcn_s_setprio(0);
    }
    __builtin_amdgcn_s_barrier();   // buf bc free for restage
    bc = (bc + 1 == NBUF) ? 0 : bc + 1;
  }

  const int row0 = (int)m0 + wr * 64, colb = (int)n0 + wc * 64;
#pragma unroll
  for (int m = 0; m < 4; m++)
#pragma unroll
    for (int n = 0; n < 4; n++)
#pragma unroll
      for (int j = 0; j < 4; j++) {
        const int r = row0 + m * 16 + lg * 4 + j;
        const int c = colb + n * 16 + lr;
        const float v = acc[m][n][j];
        if constexpr (EPI == 0) {
          bf16_t hi = (bf16_t)v;
          ((bf16_t*)C0)[(size_t)r * N + c] = hi;
          ((bf16_t*)C1)[(size_t)r * N + c] = (bf16_t)(v - (float)hi);
        } else if constexpr (EPI == 1) {
          const int bb = r >> 11, ss = r & 2047;
          ((bf16_t*)C0)[((size_t)bb * 2048 + c) * 2048 + ss] = (bf16_t)v;
        } else if constexpr (EPI == 2) {
          ((float*)C0)[(size_t)r * N + c] = v;
        } else {
          ((bf16_t*)C0)[(size_t)r * N + c] = (bf16_t)fmaxf(v, 0.f);
        }
      }
}

// ---------------- flash attention (R4 structure + XCD-aware block remap) ----------------
__global__ __launch_bounds__(256, 2) void attn_k(
    const bf16_t* __restrict__ qh, const bf16_t* __restrict__ ql,
    const bf16_t* __restrict__ kh, const bf16_t* __restrict__ kl,
    const bf16_t* __restrict__ vT, bf16_t* __restrict__ out) {
  __shared__ __align__(16) bf16_t sKh[2 * 8192];   // 2 x [64][128]
  __shared__ __align__(16) bf16_t sKl[2 * 8192];
  __shared__ __align__(16) bf16_t plds[4][1024];   // per-wave [16 rows][64 kv]

  // XCD-aware remap: all 16 q-blocks of one bh land on the same XCD (fid%8).
  const int fid = blockIdx.y * 16 + blockIdx.x;
  const int qt = fid >> 5;
  const int bh = (fid & 7) * 4 + ((fid >> 3) & 3);
  const int b = bh >> 4, h = bh & 15;
  const int wv = threadIdx.x >> 6, lane = threadIdx.x & 63, lr = lane & 15, lg = lane >> 4;
  const size_t tok0 = (size_t)b * 2048 + qt * 128 + wv * 16;  // tile0; tile1 = +64
  bf16_t* pw = &plds[wv][0];

  auto STAGE = [&](int bufi, int kv0n) {
#pragma unroll
    for (int i = 0; i < 4; i++) {
      const int tt = wv * 4 + i;                    // instr idx 0..15, 4 rows each
      const int r = tt * 4 + (lane >> 4);           // K-row 0..63
      const int ce = ((lane & 15) ^ (r & 7)) * 8;   // pre-swizzled source column
      const size_t gofs = ((size_t)b * 2048 + kv0n + r) * 2048 + h * 128 + ce;
      gload16(kh + gofs, (void*)&sKh[bufi * 8192 + tt * 512]);
      gload16(kl + gofs, (void*)&sKl[bufi * 8192 + tt * 512]);
    }
  };

  bf16x8 qhf[2][4], qlf[2][4];
#pragma unroll
  for (int t = 0; t < 2; t++) {
    const bf16_t* qp = qh + (tok0 + t * 64 + lr) * 2048 + h * 128 + lg * 8;
    const bf16_t* qp2 = ql + (tok0 + t * 64 + lr) * 2048 + h * 128 + lg * 8;
#pragma unroll
    for (int ks = 0; ks < 4; ks++) {
      qhf[t][ks] = *(const bf16x8*)(qp + ks * 32);
      qlf[t][ks] = *(const bf16x8*)(qp2 + ks * 32);
    }
  }
  f32x4 oacc[2][8] = {};
  float mrun[2][4] = {{-1e30f, -1e30f, -1e30f, -1e30f}, {-1e30f, -1e30f, -1e30f, -1e30f}};
  float lrun[2][4] = {{0.f, 0.f, 0.f, 0.f}, {0.f, 0.f, 0.f, 0.f}};
  const bf16_t* vbase = vT + ((size_t)b * 2048 + h * 128 + lr) * 2048;
  const float sc = 0.08838834764831845f;

  STAGE(0, 0);
  for (int c = 0; c < 32; c++) {
    const int kv0 = c * 64;
    if (c + 1 < 32) {
      STAGE((c + 1) & 1, kv0 + 64);
      asm volatile("s_waitcnt vmcnt(8)" ::: "memory");
    } else {
      asm volatile("s_waitcnt vmcnt(0)" ::: "memory");
    }
    __builtin_amdgcn_s_barrier();

    const int bufo = (c & 1) * 8192;
    f32x4 s[2][4] = {};
#pragma unroll
    for (int nb = 0; nb < 4; nb++) {
      const int rbase = bufo + (nb * 16 + lr) * 128;
#pragma unroll
      for (int ks = 0; ks < 4; ks++) {
        const int u = (((ks * 4 + lg) ^ (lr & 7)) * 8);
        bf16x8 kf = *(const bf16x8*)&sKh[rbase + u];
        bf16x8 kg = *(const bf16x8*)&sKl[rbase + u];
        s[0][nb] = mfma16(qhf[0][ks], kf, s[0][nb]);
        s[1][nb] = mfma16(qhf[1][ks], kf, s[1][nb]);
        s[0][nb] = mfma16(qlf[0][ks], kf, s[0][nb]);
        s[1][nb] = mfma16(qlf[1][ks], kf, s[1][nb]);
        s[0][nb] = mfma16(qhf[0][ks], kg, s[0][nb]);
        s[1][nb] = mfma16(qhf[1][ks], kg, s[1][nb]);
      }
    }

#pragma unroll
    for (int t = 0; t < 2; t++) {
#pragma unroll
      for (int nb = 0; nb < 4; nb++) s[t][nb] *= sc;
      float resc[4];
#pragma unroll
      for (int j = 0; j < 4; j++) {
        float mx = fmaxf(fmaxf(s[t][0][j], s[t][1][j]), fmaxf(s[t][2][j], s[t][3][j]));
        mx = fmaxf(mx, __shfl_xor(mx, 1)); mx = fmaxf(mx, __shfl_xor(mx, 2));
        mx = fmaxf(mx, __shfl_xor(mx, 4)); mx = fmaxf(mx, __shfl_xor(mx, 8));
        const float mnew = fmaxf(mrun[t][j], mx);
        resc[j] = __expf(mrun[t][j] - mnew);
        float rsum = 0.f;
#pragma unroll
        for (int nb = 0; nb < 4; nb++) {
          const float p = __expf(s[t][nb][j] - mnew);
          s[t][nb][j] = p;
          rsum += p;
        }
        rsum += __shfl_xor(rsum, 1); rsum += __shfl_xor(rsum, 2);
        rsum += __shfl_xor(rsum, 4); rsum += __shfl_xor(rsum, 8);
        lrun[t][j] = lrun[t][j] * resc[j] + rsum;
        mrun[t][j] = mnew;
      }
#pragma unroll
      for (int dt = 0; dt < 8; dt++)
#pragma unroll
        for (int j = 0; j < 4; j++) oacc[t][dt][j] *= resc[j];

#pragma unroll
      for (int nb = 0; nb < 4; nb++) {
        const int unit = nb * 2 + (lr >> 3);
#pragma unroll
        for (int j = 0; j < 4; j++) {
          const int row = lg * 4 + j;
          pw[row * 64 + ((unit ^ (row & 7)) * 8) + (lr & 7)] = (bf16_t)s[t][nb][j];
        }
      }
      bf16x8 pa0 = *(const bf16x8*)&pw[lr * 64 + ((lg ^ (lr & 7)) * 8)];
      bf16x8 pa1 = *(const bf16x8*)&pw[lr * 64 + (((4 + lg) ^ (lr & 7)) * 8)];

      const bf16_t* vp = vbase + kv0 + lg * 8;
#pragma unroll
      for (int dt = 0; dt < 8; dt++) {
        bf16x8 v0 = *(const bf16x8*)(vp + (size_t)dt * 16 * 2048);
        bf16x8 v1 = *(const bf16x8*)(vp + (size_t)dt * 16 * 2048 + 32);
        oacc[t][dt] = mfma16(pa0, v0, oacc[t][dt]);
        oacc[t][dt] = mfma16(pa1, v1, oacc[t][dt]);
      }
    }
    asm volatile("" ::: "memory");
    __builtin_amdgcn_s_barrier();
  }

#pragma unroll
  for (int t = 0; t < 2; t++)
#pragma unroll
    for (int j = 0; j < 4; j++) {
      const float inv = 1.f / lrun[t][j];
      const size_t rbase = (tok0 + t * 64 + lg * 4 + j) * 2048 + h * 128 + lr;
#pragma unroll
      for (int dt = 0; dt < 8; dt++) out[rbase + dt * 16] = (bf16_t)(oacc[t][dt][j] * inv);
    }
}

// ---------------- fused residual + LayerNorm ----------------
__global__ __launch_bounds__(256) void ln_k(
    const float* __restrict__ X, const float* __restrict__ R,
    const float* __restrict__ G, const float* __restrict__ Bt,
    float* __restrict__ O32, bf16_t* __restrict__ O16) {
  const int t = blockIdx.x, tid = threadIdx.x;
  const float4* xp = (const float4*)(X + (size_t)t * 2048);
  const float4* rp = (const float4*)(R + (size_t)t * 2048);
  float4 v0 = xp[tid], w0 = rp[tid];
  float4 v1 = xp[tid + 256], w1 = rp[tid + 256];
  v0.x += w0.x; v0.y += w0.y; v0.z += w0.z; v0.w += w0.w;
  v1.x += w1.x; v1.y += w1.y; v1.z += w1.z; v1.w += w1.w;
  float sum = v0.x + v0.y + v0.z + v0.w + v1.x + v1.y + v1.z + v1.w;
  float sq = v0.x * v0.x + v0.y * v0.y + v0.z * v0.z + v0.w * v0.w +
             v1.x * v1.x + v1.y * v1.y + v1.z * v1.z + v1.w * v1.w;
  for (int d = 1; d < 64; d <<= 1) { sum += __shfl_xor(sum, d); sq += __shfl_xor(sq, d); }
  __shared__ float s1[4], s2[4];
  const int wv = tid >> 6, lane = tid & 63;
  if (lane == 0) { s1[wv] = sum; s2[wv] = sq; }
  __syncthreads();
  const float tot = s1[0] + s1[1] + s1[2] + s1[3];
  const float tsq = s2[0] + s2[1] + s2[2] + s2[3];
  const float mu = tot * (1.f / 2048.f);
  const float var = tsq * (1.f / 2048.f) - mu * mu;
  const float rs = 1.f / sqrtf(var + 1e-5f);
  const float4* gp = (const float4*)G;
  const float4* bp = (const float4*)Bt;
  float4 g0 = gp[tid], g1v = gp[tid + 256], b0 = bp[tid], b1v = bp[tid + 256];
  float4 o0, o1;
  o0.x = (v0.x - mu) * rs * g0.x + b0.x; o0.y = (v0.y - mu) * rs * g0.y + b0.y;
  o0.z = (v0.z - mu) * rs * g0.z + b0.z; o0.w = (v0.w - mu) * rs * g0.w + b0.w;
  o1.x = (v1.x - mu) * rs * g1v.x + b1v.x; o1.y = (v1.y - mu) * rs * g1v.y + b1v.y;
  o1.z = (v1.z - mu) * rs * g1v.z + b1v.z; o1.w = (v1.w - mu) * rs * g1v.w + b1v.w;
  ((float4*)(O32 + (size_t)t * 2048))[tid] = o0;
  ((float4*)(O32 + (size_t)t * 2048))[tid + 256] = o1;
  if (O16) {
    bf16x4 h0, h1;
    h0[0] = (bf16_t)o0.x; h0[1] = (bf16_t)o0.y; h0[2] = (bf16_t)o0.z; h0[3] = (bf16_t)o0.w;
    h1[0] = (bf16_t)o1.x; h1[1] = (bf16_t)o1.y; h1[2] = (bf16_t)o1.z; h1[3] = (bf16_t)o1.w;
    *(bf16x4*)&O16[(size_t)t * 2048 + tid * 4] = h0;
    *(bf16x4*)&O16[(size_t)t * 2048 + 1024 + tid * 4] = h1;
  }
}

// ---------------- launch ----------------
extern "C" void kernel_launch(void* const* d_in, const int* in_sizes, int n_in,
                              void* d_out, int out_size, void* d_ws, size_t ws_size,
                              hipStream_t stream) {
  const float* x  = (const float*)d_in[0];
  const float* Wq = (const float*)d_in[1];
  const float* Wk = (const float*)d_in[2];
  const float* Wv = (const float*)d_in[3];
  const float* Wo = (const float*)d_in[4];
  const float* W1 = (const float*)d_in[5];
  const float* W2 = (const float*)d_in[6];
  const float* g1 = (const float*)d_in[7];
  const float* b1 = (const float*)d_in[8];
  const float* g2 = (const float*)d_in[9];
  const float* b2 = (const float*)d_in[10];
  float* out = (float*)d_out;
  char* ws = (char*)d_ws;

  constexpr size_t SZB = (size_t)4096 * 2048 * 2;  // one bf16 [4096][2048] buffer
  bf16_t* xh = (bf16_t*)(ws + 0 * SZB);
  bf16_t* xl = (bf16_t*)(ws + 1 * SZB);
  bf16_t* qh = (bf16_t*)(ws + 2 * SZB);
  bf16_t* ql = (bf16_t*)(ws + 3 * SZB);
  bf16_t* kh = (bf16_t*)(ws + 4 * SZB);
  bf16_t* kl = (bf16_t*)(ws + 5 * SZB);
  bf16_t* vt = (bf16_t*)(ws + 6 * SZB);
  bf16_t* at = (bf16_t*)(ws + 7 * SZB);
  float* o32 = (float*)(ws + 8 * SZB);
  bf16_t* wt = (bf16_t*)(ws + 8 * SZB + (size_t)4096 * 2048 * 4);
  double* red = (double*)(ws + 8 * SZB + (size_t)4096 * 2048 * 4 + (size_t)8192 * 2048 * 2);
  double* sums = red + 8192;
  // aliases (phase-disjoint lifetimes)
  float* h1 = (float*)ws;       // over xh+xl
  bf16_t* h1b = qh;             // over qh
  bf16_t* f1 = kh;              // over kh,kl,vt,at (exactly 67.1 MB)
  float* g32 = o32;             // over o32
  (void)in_sizes; (void)n_in; (void)out_size; (void)ws_size;

  abssum_all<<<dim3(1024, 6), 256, 0, stream>>>(Wq, Wk, Wv, Wo, W1, W2, red);
  abssum_fin<<<6, 256, 0, stream>>>(red, sums);
  split_x_k<<<8192, 256, 0, stream>>>(x, xh, xl);

  // Q
  ternarize_k<<<4096, 256, 0, stream>>>(Wq, wt, sums + 0, 4194304.0);
  gemm8<0, true><<<dim3(8, 32), 512, 0, stream>>>(xh, xl, wt, qh, ql, 4096, 2048, 2048);
  // K
  ternarize_k<<<4096, 256, 0, stream>>>(Wk, wt, sums + 1, 4194304.0);
  gemm8<0, true><<<dim3(8, 32), 512, 0, stream>>>(xh, xl, wt, kh, kl, 4096, 2048, 2048);
  // V (plain A, transposed store)
  ternarize_k<<<4096, 256, 0, stream>>>(Wv, wt, sums + 2, 4194304.0);
  gemm8<1, false><<<dim3(8, 32), 512, 0, stream>>>(xh, nullptr, wt, vt, nullptr, 4096, 2048, 2048);
  // attention (q-tile 128 -> grid 16 x 32, XCD-remapped in-kernel)
  attn_k<<<dim3(16, 32), 256, 0, stream>>>(qh, ql, kh, kl, vt, at);
  // O projection -> f32
  ternarize_k<<<4096, 256, 0, stream>>>(Wo, wt, sums + 3, 4194304.0);
  gemm8<2, false><<<dim3(8, 32), 512, 0, stream>>>(at, nullptr, wt, o32, nullptr, 4096, 2048, 2048);
  // LN1 (residual x + o32) -> h1 (f32) + h1b (bf16)
  ln_k<<<4096, 256, 0, stream>>>(x, o32, g1, b1, h1, h1b);
  // FF1 + relu
  ternarize_k<<<16384, 256, 0, stream>>>(W1, wt, sums + 4, 16777216.0);
  gemm8<3, false><<<dim3(32, 32), 512, 0, stream>>>(h1b, nullptr, wt, f1, nullptr, 4096, 8192, 2048);
  // FF2 -> f32
  ternarize_k<<<16384, 256, 0, stream>>>(W2, wt, sums + 5, 16777216.0);
  gemm8<2, false><<<dim3(8, 32), 512, 0, stream>>>(f1, nullptr, wt, g32, nullptr, 4096, 2048, 8192);
  // LN2 -> out
  ln_k<<<4096, 256, 0, stream>>>(h1, g32, g2, b2, out, nullptr);
}

// Round 6
// 1004.877 us; speedup vs baseline: 1.0499x; 1.0499x over previous
//
#include <hip/hip_runtime.h>
#include <hip/hip_bf16.h>

typedef __bf16 bf16_t;
typedef __bf16 bf16x8 __attribute__((ext_vector_type(8)));
typedef __bf16 bf16x4 __attribute__((ext_vector_type(4)));
typedef float f32x4 __attribute__((ext_vector_type(4)));
typedef int i32x4 __attribute__((ext_vector_type(4)));

__device__ __forceinline__ f32x4 mfma16(bf16x8 a, bf16x8 b, f32x4 c) {
  return __builtin_amdgcn_mfma_f32_16x16x32_bf16(a, b, c, 0, 0, 0);
}

__device__ __forceinline__ void gload16(const void* g, void* l) {
  __builtin_amdgcn_global_load_lds(
      (const __attribute__((address_space(1))) void*)g,
      (__attribute__((address_space(3))) void*)l, 16, 0, 0);
}

// ---------------- ternary threshold: deterministic fp64 reduction (fused, 6 weights) --------
__global__ void abssum_all(const float* __restrict__ W0, const float* __restrict__ W1_,
                           const float* __restrict__ W2_, const float* __restrict__ W3,
                           const float* __restrict__ W4, const float* __restrict__ W5,
                           double* __restrict__ partial) {
  __shared__ double sd[256];
  const int w = blockIdx.y, tid = threadIdx.x;
  const float* W = (w == 0) ? W0 : (w == 1) ? W1_ : (w == 2) ? W2_ : (w == 3) ? W3 : (w == 4) ? W4 : W5;
  const int n4 = (w < 4) ? 1048576 : 4194304;
  double s = 0.0;
  for (int i = blockIdx.x * 256 + tid; i < n4; i += 262144) {
    float4 v = ((const float4*)W)[i];
    s += (double)fabsf(v.x); s += (double)fabsf(v.y);
    s += (double)fabsf(v.z); s += (double)fabsf(v.w);
  }
  sd[tid] = s; __syncthreads();
  for (int st = 128; st > 0; st >>= 1) { if (tid < st) sd[tid] += sd[tid + st]; __syncthreads(); }
  if (tid == 0) partial[w * 1024 + blockIdx.x] = sd[0];
}

__global__ void abssum_fin(const double* __restrict__ partial, double* __restrict__ sums) {
  __shared__ double sd[256];
  const int tid = threadIdx.x;
  const double* p = partial + blockIdx.x * 1024;
  double s = p[tid] + p[tid + 256] + p[tid + 512] + p[tid + 768];
  sd[tid] = s; __syncthreads();
  for (int st = 128; st > 0; st >>= 1) { if (tid < st) sd[tid] += sd[tid + st]; __syncthreads(); }
  if (tid == 0) sums[blockIdx.x] = sd[0];
}

__global__ void ternarize_k(const float* __restrict__ W, bf16_t* __restrict__ out,
                            const double* __restrict__ sum, double n) {
  const double thr = sum[0] / n;
  const int i = blockIdx.x * 256 + threadIdx.x;  // float4 index; grid sized exactly
  float4 v = ((const float4*)W)[i];
  bf16x4 o;
  float t;
  t = ((double)fabsf(v.x) > thr) ? (v.x > 0.f ? 1.f : -1.f) : 0.f; o[0] = (bf16_t)t;
  t = ((double)fabsf(v.y) > thr) ? (v.y > 0.f ? 1.f : -1.f) : 0.f; o[1] = (bf16_t)t;
  t = ((double)fabsf(v.z) > thr) ? (v.z > 0.f ? 1.f : -1.f) : 0.f; o[2] = (bf16_t)t;
  t = ((double)fabsf(v.w) > thr) ? (v.w > 0.f ? 1.f : -1.f) : 0.f; o[3] = (bf16_t)t;
  *(bf16x4*)&out[(size_t)i * 4] = o;
}

// ---------------- x -> hi/lo bf16 split ----------------
__global__ void split_x_k(const float* __restrict__ X, bf16_t* __restrict__ xh, bf16_t* __restrict__ xl) {
  const int i = blockIdx.x * 256 + threadIdx.x;  // float4 index
  float4 v = ((const float4*)X)[i];
  bf16x4 h, l;
  h[0] = (bf16_t)v.x; l[0] = (bf16_t)(v.x - (float)h[0]);
  h[1] = (bf16_t)v.y; l[1] = (bf16_t)(v.y - (float)h[1]);
  h[2] = (bf16_t)v.z; l[2] = (bf16_t)(v.z - (float)h[2]);
  h[3] = (bf16_t)v.w; l[3] = (bf16_t)(v.w - (float)h[3]);
  *(bf16x4*)&xh[(size_t)i * 4] = h;
  *(bf16x4*)&xl[(size_t)i * 4] = l;
}

// ---------------- GEMM v3: m201-style phased schedule ----------------
// C[t][o] = sum_k A[t][k] * W[o][k]  (W ternary bf16 [N][K] row-major).
// BN=256, BK=64, 8 waves (2M x 4N). Non-split: BM=128 (per-wave 64x64);
// SPLITA: BM=64, A-hi + A-lo staged (per-wave 32x64). NBUF=3, depth-2
// prefetch, vmcnt(6) once per K-tile (never drained in steady state).
// Per K-tile: 2 phases of exactly 16 MFMA:
//   {ds_reads; 3 gload_lds; barrier; lgkmcnt(0); setprio(1); 16 MFMA; setprio(0); barrier}
// XOR-swizzled LDS via pre-swizzled global source (slot s holds unit s^(row&7)).
// EPI: 0 = split-store (C0 hi, C1 lo), 1 = vT transposed store, 2 = f32, 3 = relu bf16
template <int EPI, bool SPLITA>
__global__ __launch_bounds__(512, 2) void gemmP(
    const bf16_t* __restrict__ Ah, const bf16_t* __restrict__ Al,
    const bf16_t* __restrict__ Bw,
    void* __restrict__ C0, void* __restrict__ C1,
    int M, int N, int K) {
  constexpr int BM = SPLITA ? 64 : 128;
  constexpr int MREP = SPLITA ? 2 : 4;
  constexpr int ABUF = BM * 64;
  constexpr int BBUF = 256 * 64;
  __shared__ __align__(16) bf16_t sA[3][ABUF];
  __shared__ __align__(16) bf16_t sA2[SPLITA ? 3 : 1][SPLITA ? ABUF : 8];
  __shared__ __align__(16) bf16_t sB[3][BBUF];

  const int tid = threadIdx.x;
  const int wid = tid >> 6, lane = tid & 63, lr = lane & 15, lg = lane >> 4;
  const int wr = wid >> 2, wc = wid & 3;
  const size_t Ks = (size_t)K;

  // XCD-chunked block swizzle (all grids have nwg % 8 == 0)
  const int nwg = gridDim.x * gridDim.y;
  const int bid0 = blockIdx.y * gridDim.x + blockIdx.x;
  const int swz = (bid0 & 7) * (nwg >> 3) + (bid0 >> 3);
  const int bx = swz % gridDim.x, by = swz / gridDim.x;
  const size_t m0 = (size_t)by * BM, n0 = (size_t)bx * 256;
  const int nt = K / 64;

  f32x4 acc[MREP][4] = {};

  // stage half of K-tile kt into buffer bi (3 gload_lds per thread per half)
  auto STAGEH = [&](int bi, int kt, int half) {
    const size_t ko = (size_t)kt * 64;
    if (half == 0) {
#pragma unroll
      for (int i = 0; i < BM / 64; i++) {
        const int t = i * 512 + tid;
        const int r = t >> 3;
        const int su = (t & 7) ^ (r & 7);
        const int lo = (i * 512 + wid * 64) * 8;   // wave-uniform LDS base
        gload16(Ah + (m0 + r) * Ks + ko + su * 8, (void*)&sA[bi][lo]);
        if constexpr (SPLITA) gload16(Al + (m0 + r) * Ks + ko + su * 8, (void*)&sA2[bi][lo]);
      }
      {  // B rows 0..63
        const int r = tid >> 3;
        const int su = (tid & 7) ^ (r & 7);
        gload16(Bw + (n0 + r) * Ks + ko + su * 8, (void*)&sB[bi][(wid * 64) * 8]);
      }
    } else {
#pragma unroll
      for (int i = 1; i < 4; i++) {  // B rows 64..255
        const int t = i * 512 + tid;
        const int r = t >> 3;
        const int su = (t & 7) ^ (r & 7);
        gload16(Bw + (n0 + r) * Ks + ko + su * 8, (void*)&sB[bi][(i * 512 + wid * 64) * 8]);
      }
    }
  };
  auto LDA = [&](const bf16_t* base, int m, int k) -> bf16x8 {
    const int row = wr * (BM / 2) + m * 16 + lr;
    const int u = (k * 4 + lg) ^ (lr & 7);         // row&7 == lr&7
    return *(const bf16x8*)&base[row * 64 + u * 8];
  };
  auto LDB = [&](const bf16_t* base, int n, int k) -> bf16x8 {
    const int row = wc * 64 + n * 16 + lr;
    const int u = (k * 4 + lg) ^ (lr & 7);
    return *(const bf16x8*)&base[row * 64 + u * 8];
  };

  // prologue: tiles 0 and 1 staged; publish tile 0
  STAGEH(0, 0, 0); STAGEH(0, 0, 1);
  STAGEH(1, 1, 0); STAGEH(1, 1, 1);
  asm volatile("s_waitcnt vmcnt(6)" ::: "memory");
  __builtin_amdgcn_s_barrier();

  int bc = 0, bs = 2;
  for (int kt = 0; kt < nt; kt++) {
    const bool pf = (kt + 2 < nt);
    // ================= phase 1 =================
    bf16x8 a[MREP][2], bfr[4][2];
#pragma unroll
    for (int m = 0; m < MREP; m++)
#pragma unroll
      for (int k = 0; k < 2; k++) a[m][k] = LDA(&sA[bc][0], m, k);
    if constexpr (SPLITA) {
#pragma unroll
      for (int n = 0; n < 4; n++)
#pragma unroll
        for (int k = 0; k < 2; k++) bfr[n][k] = LDB(&sB[bc][0], n, k);
    } else {
#pragma unroll
      for (int n = 0; n < 2; n++)
#pragma unroll
        for (int k = 0; k < 2; k++) bfr[n][k] = LDB(&sB[bc][0], n, k);
    }
    if (pf) STAGEH(bs, kt + 2, 0);
    __builtin_amdgcn_s_barrier();
    asm volatile("s_waitcnt lgkmcnt(0)" ::: "memory");
    __builtin_amdgcn_sched_barrier(0);
    __builtin_amdgcn_s_setprio(1);
    if constexpr (SPLITA) {
#pragma unroll
      for (int k = 0; k < 2; k++)
#pragma unroll
        for (int m = 0; m < MREP; m++)
#pragma unroll
          for (int n = 0; n < 4; n++) acc[m][n] = mfma16(a[m][k], bfr[n][k], acc[m][n]);
    } else {
#pragma unroll
      for (int k = 0; k < 2; k++)
#pragma unroll
        for (int m = 0; m < MREP; m++)
#pragma unroll
          for (int n = 0; n < 2; n++) acc[m][n] = mfma16(a[m][k], bfr[n][k], acc[m][n]);
    }
    __builtin_amdgcn_s_setprio(0);
    __builtin_amdgcn_s_barrier();
    // ================= phase 2 =================
    if constexpr (SPLITA) {
#pragma unroll
      for (int m = 0; m < MREP; m++)
#pragma unroll
        for (int k = 0; k < 2; k++) a[m][k] = LDA(&sA2[bc][0], m, k);
    } else {
#pragma unroll
      for (int n = 0; n < 2; n++)
#pragma unroll
        for (int k = 0; k < 2; k++) bfr[n + 2][k] = LDB(&sB[bc][0], n + 2, k);
    }
    if (pf) STAGEH(bs, kt + 2, 1);
    if (kt + 1 < nt) {
      if (pf) asm volatile("s_waitcnt vmcnt(6)" ::: "memory");   // publish tile kt+1
      else    asm volatile("s_waitcnt vmcnt(0)" ::: "memory");
    }
    __builtin_amdgcn_s_barrier();
    asm volatile("s_waitcnt lgkmcnt(0)" ::: "memory");
    __builtin_amdgcn_sched_barrier(0);
    __builtin_amdgcn_s_setprio(1);
    if constexpr (SPLITA) {
#pragma unroll
      for (int k = 0; k < 2; k++)
#pragma unroll
        for (int m = 0; m < MREP; m++)
#pragma unroll
          for (int n = 0; n < 4; n++) acc[m][n] = mfma16(a[m][k], bfr[n][k], acc[m][n]);
    } else {
#pragma unroll
      for (int k = 0; k < 2; k++)
#pragma unroll
        for (int m = 0; m < MREP; m++)
#pragma unroll
          for (int n = 0; n < 2; n++) acc[m][n + 2] = mfma16(a[m][k], bfr[n + 2][k], acc[m][n + 2]);
    }
    __builtin_amdgcn_s_setprio(0);
    __builtin_amdgcn_s_barrier();
    bc = (bc + 1 == 3) ? 0 : bc + 1;
    bs = (bs + 1 == 3) ? 0 : bs + 1;
  }

  const int row0 = (int)m0 + wr * (BM / 2), colb = (int)n0 + wc * 64;
#pragma unroll
  for (int m = 0; m < MREP; m++)
#pragma unroll
    for (int n = 0; n < 4; n++)
#pragma unroll
      for (int j = 0; j < 4; j++) {
        const int r = row0 + m * 16 + lg * 4 + j;
        const int c = colb + n * 16 + lr;
        const float v = acc[m][n][j];
        if constexpr (EPI == 0) {
          bf16_t hi = (bf16_t)v;
          ((bf16_t*)C0)[(size_t)r * N + c] = hi;
          ((bf16_t*)C1)[(size_t)r * N + c] = (bf16_t)(v - (float)hi);
        } else if constexpr (EPI == 1) {
          const int bb = r >> 11, ss = r & 2047;
          ((bf16_t*)C0)[((size_t)bb * 2048 + c) * 2048 + ss] = (bf16_t)v;
        } else if constexpr (EPI == 2) {
          ((float*)C0)[(size_t)r * N + c] = v;
        } else {
          ((bf16_t*)C0)[(size_t)r * N + c] = (bf16_t)fmaxf(v, 0.f);
        }
      }
  (void)M;
}

// ---------------- flash attention (R4 structure + XCD-aware block remap) ----------------
__global__ __launch_bounds__(256, 2) void attn_k(
    const bf16_t* __restrict__ qh, const bf16_t* __restrict__ ql,
    const bf16_t* __restrict__ kh, const bf16_t* __restrict__ kl,
    const bf16_t* __restrict__ vT, bf16_t* __restrict__ out) {
  __shared__ __align__(16) bf16_t sKh[2 * 8192];   // 2 x [64][128]
  __shared__ __align__(16) bf16_t sKl[2 * 8192];
  __shared__ __align__(16) bf16_t plds[4][1024];   // per-wave [16 rows][64 kv]

  // XCD-aware remap: all 16 q-blocks of one bh land on the same XCD (fid%8).
  const int fid = blockIdx.y * 16 + blockIdx.x;
  const int qt = fid >> 5;
  const int bh = (fid & 7) * 4 + ((fid >> 3) & 3);
  const int b = bh >> 4, h = bh & 15;
  const int wv = threadIdx.x >> 6, lane = threadIdx.x & 63, lr = lane & 15, lg = lane >> 4;
  const size_t tok0 = (size_t)b * 2048 + qt * 128 + wv * 16;  // tile0; tile1 = +64
  bf16_t* pw = &plds[wv][0];

  auto STAGE = [&](int bufi, int kv0n) {
#pragma unroll
    for (int i = 0; i < 4; i++) {
      const int tt = wv * 4 + i;                    // instr idx 0..15, 4 rows each
      const int r = tt * 4 + (lane >> 4);           // K-row 0..63
      const int ce = ((lane & 15) ^ (r & 7)) * 8;   // pre-swizzled source column
      const size_t gofs = ((size_t)b * 2048 + kv0n + r) * 2048 + h * 128 + ce;
      gload16(kh + gofs, (void*)&sKh[bufi * 8192 + tt * 512]);
      gload16(kl + gofs, (void*)&sKl[bufi * 8192 + tt * 512]);
    }
  };

  bf16x8 qhf[2][4], qlf[2][4];
#pragma unroll
  for (int t = 0; t < 2; t++) {
    const bf16_t* qp = qh + (tok0 + t * 64 + lr) * 2048 + h * 128 + lg * 8;
    const bf16_t* qp2 = ql + (tok0 + t * 64 + lr) * 2048 + h * 128 + lg * 8;
#pragma unroll
    for (int ks = 0; ks < 4; ks++) {
      qhf[t][ks] = *(const bf16x8*)(qp + ks * 32);
      qlf[t][ks] = *(const bf16x8*)(qp2 + ks * 32);
    }
  }
  f32x4 oacc[2][8] = {};
  float mrun[2][4] = {{-1e30f, -1e30f, -1e30f, -1e30f}, {-1e30f, -1e30f, -1e30f, -1e30f}};
  float lrun[2][4] = {{0.f, 0.f, 0.f, 0.f}, {0.f, 0.f, 0.f, 0.f}};
  const bf16_t* vbase = vT + ((size_t)b * 2048 + h * 128 + lr) * 2048;
  const float sc = 0.08838834764831845f;

  STAGE(0, 0);
  for (int c = 0; c < 32; c++) {
    const int kv0 = c * 64;
    if (c + 1 < 32) {
      STAGE((c + 1) & 1, kv0 + 64);
      asm volatile("s_waitcnt vmcnt(8)" ::: "memory");
    } else {
      asm volatile("s_waitcnt vmcnt(0)" ::: "memory");
    }
    __builtin_amdgcn_s_barrier();

    const int bufo = (c & 1) * 8192;
    f32x4 s[2][4] = {};
#pragma unroll
    for (int nb = 0; nb < 4; nb++) {
      const int rbase = bufo + (nb * 16 + lr) * 128;
#pragma unroll
      for (int ks = 0; ks < 4; ks++) {
        const int u = (((ks * 4 + lg) ^ (lr & 7)) * 8);
        bf16x8 kf = *(const bf16x8*)&sKh[rbase + u];
        bf16x8 kg = *(const bf16x8*)&sKl[rbase + u];
        s[0][nb] = mfma16(qhf[0][ks], kf, s[0][nb]);
        s[1][nb] = mfma16(qhf[1][ks], kf, s[1][nb]);
        s[0][nb] = mfma16(qlf[0][ks], kf, s[0][nb]);
        s[1][nb] = mfma16(qlf[1][ks], kf, s[1][nb]);
        s[0][nb] = mfma16(qhf[0][ks], kg, s[0][nb]);
        s[1][nb] = mfma16(qhf[1][ks], kg, s[1][nb]);
      }
    }

#pragma unroll
    for (int t = 0; t < 2; t++) {
#pragma unroll
      for (int nb = 0; nb < 4; nb++) s[t][nb] *= sc;
      float resc[4];
#pragma unroll
      for (int j = 0; j < 4; j++) {
        float mx = fmaxf(fmaxf(s[t][0][j], s[t][1][j]), fmaxf(s[t][2][j], s[t][3][j]));
        mx = fmaxf(mx, __shfl_xor(mx, 1)); mx = fmaxf(mx, __shfl_xor(mx, 2));
        mx = fmaxf(mx, __shfl_xor(mx, 4)); mx = fmaxf(mx, __shfl_xor(mx, 8));
        const float mnew = fmaxf(mrun[t][j], mx);
        resc[j] = __expf(mrun[t][j] - mnew);
        float rsum = 0.f;
#pragma unroll
        for (int nb = 0; nb < 4; nb++) {
          const float p = __expf(s[t][nb][j] - mnew);
          s[t][nb][j] = p;
          rsum += p;
        }
        rsum += __shfl_xor(rsum, 1); rsum += __shfl_xor(rsum, 2);
        rsum += __shfl_xor(rsum, 4); rsum += __shfl_xor(rsum, 8);
        lrun[t][j] = lrun[t][j] * resc[j] + rsum;
        mrun[t][j] = mnew;
      }
#pragma unroll
      for (int dt = 0; dt < 8; dt++)
#pragma unroll
        for (int j = 0; j < 4; j++) oacc[t][dt][j] *= resc[j];

#pragma unroll
      for (int nb = 0; nb < 4; nb++) {
        const int unit = nb * 2 + (lr >> 3);
#pragma unroll
        for (int j = 0; j < 4; j++) {
          const int row = lg * 4 + j;
          pw[row * 64 + ((unit ^ (row & 7)) * 8) + (lr & 7)] = (bf16_t)s[t][nb][j];
        }
      }
      bf16x8 pa0 = *(const bf16x8*)&pw[lr * 64 + ((lg ^ (lr & 7)) * 8)];
      bf16x8 pa1 = *(const bf16x8*)&pw[lr * 64 + (((4 + lg) ^ (lr & 7)) * 8)];

      const bf16_t* vp = vbase + kv0 + lg * 8;
#pragma unroll
      for (int dt = 0; dt < 8; dt++) {
        bf16x8 v0 = *(const bf16x8*)(vp + (size_t)dt * 16 * 2048);
        bf16x8 v1 = *(const bf16x8*)(vp + (size_t)dt * 16 * 2048 + 32);
        oacc[t][dt] = mfma16(pa0, v0, oacc[t][dt]);
        oacc[t][dt] = mfma16(pa1, v1, oacc[t][dt]);
      }
    }
    asm volatile("" ::: "memory");
    __builtin_amdgcn_s_barrier();
  }

#pragma unroll
  for (int t = 0; t < 2; t++)
#pragma unroll
    for (int j = 0; j < 4; j++) {
      const float inv = 1.f / lrun[t][j];
      const size_t rbase = (tok0 + t * 64 + lg * 4 + j) * 2048 + h * 128 + lr;
#pragma unroll
      for (int dt = 0; dt < 8; dt++) out[rbase + dt * 16] = (bf16_t)(oacc[t][dt][j] * inv);
    }
}

// ---------------- fused residual + LayerNorm ----------------
__global__ __launch_bounds__(256) void ln_k(
    const float* __restrict__ X, const float* __restrict__ R,
    const float* __restrict__ G, const float* __restrict__ Bt,
    float* __restrict__ O32, bf16_t* __restrict__ O16) {
  const int t = blockIdx.x, tid = threadIdx.x;
  const float4* xp = (const float4*)(X + (size_t)t * 2048);
  const float4* rp = (const float4*)(R + (size_t)t * 2048);
  float4 v0 = xp[tid], w0 = rp[tid];
  float4 v1 = xp[tid + 256], w1 = rp[tid + 256];
  v0.x += w0.x; v0.y += w0.y; v0.z += w0.z; v0.w += w0.w;
  v1.x += w1.x; v1.y += w1.y; v1.z += w1.z; v1.w += w1.w;
  float sum = v0.x + v0.y + v0.z + v0.w + v1.x + v1.y + v1.z + v1.w;
  float sq = v0.x * v0.x + v0.y * v0.y + v0.z * v0.z + v0.w * v0.w +
             v1.x * v1.x + v1.y * v1.y + v1.z * v1.z + v1.w * v1.w;
  for (int d = 1; d < 64; d <<= 1) { sum += __shfl_xor(sum, d); sq += __shfl_xor(sq, d); }
  __shared__ float s1[4], s2[4];
  const int wv = tid >> 6, lane = tid & 63;
  if (lane == 0) { s1[wv] = sum; s2[wv] = sq; }
  __syncthreads();
  const float tot = s1[0] + s1[1] + s1[2] + s1[3];
  const float tsq = s2[0] + s2[1] + s2[2] + s2[3];
  const float mu = tot * (1.f / 2048.f);
  const float var = tsq * (1.f / 2048.f) - mu * mu;
  const float rs = 1.f / sqrtf(var + 1e-5f);
  const float4* gp = (const float4*)G;
  const float4* bp = (const float4*)Bt;
  float4 g0 = gp[tid], g1v = gp[tid + 256], b0 = bp[tid], b1v = bp[tid + 256];
  float4 o0, o1;
  o0.x = (v0.x - mu) * rs * g0.x + b0.x; o0.y = (v0.y - mu) * rs * g0.y + b0.y;
  o0.z = (v0.z - mu) * rs * g0.z + b0.z; o0.w = (v0.w - mu) * rs * g0.w + b0.w;
  o1.x = (v1.x - mu) * rs * g1v.x + b1v.x; o1.y = (v1.y - mu) * rs * g1v.y + b1v.y;
  o1.z = (v1.z - mu) * rs * g1v.z + b1v.z; o1.w = (v1.w - mu) * rs * g1v.w + b1v.w;
  ((float4*)(O32 + (size_t)t * 2048))[tid] = o0;
  ((float4*)(O32 + (size_t)t * 2048))[tid + 256] = o1;
  if (O16) {
    bf16x4 h0, h1;
    h0[0] = (bf16_t)o0.x; h0[1] = (bf16_t)o0.y; h0[2] = (bf16_t)o0.z; h0[3] = (bf16_t)o0.w;
    h1[0] = (bf16_t)o1.x; h1[1] = (bf16_t)o1.y; h1[2] = (bf16_t)o1.z; h1[3] = (bf16_t)o1.w;
    *(bf16x4*)&O16[(size_t)t * 2048 + tid * 4] = h0;
    *(bf16x4*)&O16[(size_t)t * 2048 + 1024 + tid * 4] = h1;
  }
}

// ---------------- launch ----------------
extern "C" void kernel_launch(void* const* d_in, const int* in_sizes, int n_in,
                              void* d_out, int out_size, void* d_ws, size_t ws_size,
                              hipStream_t stream) {
  const float* x  = (const float*)d_in[0];
  const float* Wq = (const float*)d_in[1];
  const float* Wk = (const float*)d_in[2];
  const float* Wv = (const float*)d_in[3];
  const float* Wo = (const float*)d_in[4];
  const float* W1 = (const float*)d_in[5];
  const float* W2 = (const float*)d_in[6];
  const float* g1 = (const float*)d_in[7];
  const float* b1 = (const float*)d_in[8];
  const float* g2 = (const float*)d_in[9];
  const float* b2 = (const float*)d_in[10];
  float* out = (float*)d_out;
  char* ws = (char*)d_ws;

  constexpr size_t SZB = (size_t)4096 * 2048 * 2;  // one bf16 [4096][2048] buffer
  bf16_t* xh = (bf16_t*)(ws + 0 * SZB);
  bf16_t* xl = (bf16_t*)(ws + 1 * SZB);
  bf16_t* qh = (bf16_t*)(ws + 2 * SZB);
  bf16_t* ql = (bf16_t*)(ws + 3 * SZB);
  bf16_t* kh = (bf16_t*)(ws + 4 * SZB);
  bf16_t* kl = (bf16_t*)(ws + 5 * SZB);
  bf16_t* vt = (bf16_t*)(ws + 6 * SZB);
  bf16_t* at = (bf16_t*)(ws + 7 * SZB);
  float* o32 = (float*)(ws + 8 * SZB);
  bf16_t* wt = (bf16_t*)(ws + 8 * SZB + (size_t)4096 * 2048 * 4);
  double* red = (double*)(ws + 8 * SZB + (size_t)4096 * 2048 * 4 + (size_t)8192 * 2048 * 2);
  double* sums = red + 8192;
  // aliases (phase-disjoint lifetimes)
  float* h1 = (float*)ws;       // over xh+xl
  bf16_t* h1b = qh;             // over qh
  bf16_t* f1 = kh;              // over kh,kl,vt,at (exactly 67.1 MB)
  float* g32 = o32;             // over o32
  (void)in_sizes; (void)n_in; (void)out_size; (void)ws_size;

  abssum_all<<<dim3(1024, 6), 256, 0, stream>>>(Wq, Wk, Wv, Wo, W1, W2, red);
  abssum_fin<<<6, 256, 0, stream>>>(red, sums);
  split_x_k<<<8192, 256, 0, stream>>>(x, xh, xl);

  // Q  (SPLITA: BM=64 -> grid (8, 64))
  ternarize_k<<<4096, 256, 0, stream>>>(Wq, wt, sums + 0, 4194304.0);
  gemmP<0, true><<<dim3(8, 64), 512, 0, stream>>>(xh, xl, wt, qh, ql, 4096, 2048, 2048);
  // K
  ternarize_k<<<4096, 256, 0, stream>>>(Wk, wt, sums + 1, 4194304.0);
  gemmP<0, true><<<dim3(8, 64), 512, 0, stream>>>(xh, xl, wt, kh, kl, 4096, 2048, 2048);
  // V (plain A, transposed store; BM=128 -> grid (8, 32))
  ternarize_k<<<4096, 256, 0, stream>>>(Wv, wt, sums + 2, 4194304.0);
  gemmP<1, false><<<dim3(8, 32), 512, 0, stream>>>(xh, nullptr, wt, vt, nullptr, 4096, 2048, 2048);
  // attention (q-tile 128 -> grid 16 x 32, XCD-remapped in-kernel)
  attn_k<<<dim3(16, 32), 256, 0, stream>>>(qh, ql, kh, kl, vt, at);
  // O projection -> f32
  ternarize_k<<<4096, 256, 0, stream>>>(Wo, wt, sums + 3, 4194304.0);
  gemmP<2, false><<<dim3(8, 32), 512, 0, stream>>>(at, nullptr, wt, o32, nullptr, 4096, 2048, 2048);
  // LN1 (residual x + o32) -> h1 (f32) + h1b (bf16)
  ln_k<<<4096, 256, 0, stream>>>(x, o32, g1, b1, h1, h1b);
  // FF1 + relu (grid (32, 32))
  ternarize_k<<<16384, 256, 0, stream>>>(W1, wt, sums + 4, 16777216.0);
  gemmP<3, false><<<dim3(32, 32), 512, 0, stream>>>(h1b, nullptr, wt, f1, nullptr, 4096, 8192, 2048);
  // FF2 -> f32
  ternarize_k<<<16384, 256, 0, stream>>>(W2, wt, sums + 5, 16777216.0);
  gemmP<2, false><<<dim3(8, 32), 512, 0, stream>>>(f1, nullptr, wt, g32, nullptr, 4096, 2048, 8192);
  // LN2 -> out
  ln_k<<<4096, 256, 0, stream>>>(h1, g32, g2, b2, out, nullptr);
}

// Round 7
// 881.398 us; speedup vs baseline: 1.1970x; 1.1401x over previous
//
#include <hip/hip_runtime.h>
#include <hip/hip_bf16.h>

typedef __bf16 bf16_t;
typedef __bf16 bf16x8 __attribute__((ext_vector_type(8)));
typedef __bf16 bf16x4 __attribute__((ext_vector_type(4)));
typedef float f32x4 __attribute__((ext_vector_type(4)));
typedef int i32x4 __attribute__((ext_vector_type(4)));

__device__ __forceinline__ f32x4 mfma16(bf16x8 a, bf16x8 b, f32x4 c) {
  return __builtin_amdgcn_mfma_f32_16x16x32_bf16(a, b, c, 0, 0, 0);
}

__device__ __forceinline__ void gload16(const void* g, void* l) {
  __builtin_amdgcn_global_load_lds(
      (const __attribute__((address_space(1))) void*)g,
      (__attribute__((address_space(3))) void*)l, 16, 0, 0);
}

// ---------------- ternary threshold: deterministic fp64 reduction (fused, 6 weights) --------
__global__ void abssum_all(const float* __restrict__ W0, const float* __restrict__ W1_,
                           const float* __restrict__ W2_, const float* __restrict__ W3,
                           const float* __restrict__ W4, const float* __restrict__ W5,
                           double* __restrict__ partial) {
  __shared__ double sd[256];
  const int w = blockIdx.y, tid = threadIdx.x;
  const float* W = (w == 0) ? W0 : (w == 1) ? W1_ : (w == 2) ? W2_ : (w == 3) ? W3 : (w == 4) ? W4 : W5;
  const int n4 = (w < 4) ? 1048576 : 4194304;
  double s = 0.0;
  for (int i = blockIdx.x * 256 + tid; i < n4; i += 262144) {
    float4 v = ((const float4*)W)[i];
    s += (double)fabsf(v.x); s += (double)fabsf(v.y);
    s += (double)fabsf(v.z); s += (double)fabsf(v.w);
  }
  sd[tid] = s; __syncthreads();
  for (int st = 128; st > 0; st >>= 1) { if (tid < st) sd[tid] += sd[tid + st]; __syncthreads(); }
  if (tid == 0) partial[w * 1024 + blockIdx.x] = sd[0];
}

__global__ void abssum_fin(const double* __restrict__ partial, double* __restrict__ sums) {
  __shared__ double sd[256];
  const int tid = threadIdx.x;
  const double* p = partial + blockIdx.x * 1024;
  double s = p[tid] + p[tid + 256] + p[tid + 512] + p[tid + 768];
  sd[tid] = s; __syncthreads();
  for (int st = 128; st > 0; st >>= 1) { if (tid < st) sd[tid] += sd[tid + st]; __syncthreads(); }
  if (tid == 0) sums[blockIdx.x] = sd[0];
}

__global__ void ternarize_k(const float* __restrict__ W, bf16_t* __restrict__ out,
                            const double* __restrict__ sum, double n) {
  const double thr = sum[0] / n;
  const int i = blockIdx.x * 256 + threadIdx.x;  // float4 index; grid sized exactly
  float4 v = ((const float4*)W)[i];
  bf16x4 o;
  float t;
  t = ((double)fabsf(v.x) > thr) ? (v.x > 0.f ? 1.f : -1.f) : 0.f; o[0] = (bf16_t)t;
  t = ((double)fabsf(v.y) > thr) ? (v.y > 0.f ? 1.f : -1.f) : 0.f; o[1] = (bf16_t)t;
  t = ((double)fabsf(v.z) > thr) ? (v.z > 0.f ? 1.f : -1.f) : 0.f; o[2] = (bf16_t)t;
  t = ((double)fabsf(v.w) > thr) ? (v.w > 0.f ? 1.f : -1.f) : 0.f; o[3] = (bf16_t)t;
  *(bf16x4*)&out[(size_t)i * 4] = o;
}

// ---------------- x -> hi/lo bf16 split ----------------
__global__ void split_x_k(const float* __restrict__ X, bf16_t* __restrict__ xh, bf16_t* __restrict__ xl) {
  const int i = blockIdx.x * 256 + threadIdx.x;  // float4 index
  float4 v = ((const float4*)X)[i];
  bf16x4 h, l;
  h[0] = (bf16_t)v.x; l[0] = (bf16_t)(v.x - (float)h[0]);
  h[1] = (bf16_t)v.y; l[1] = (bf16_t)(v.y - (float)h[1]);
  h[2] = (bf16_t)v.z; l[2] = (bf16_t)(v.z - (float)h[2]);
  h[3] = (bf16_t)v.w; l[3] = (bf16_t)(v.w - (float)h[3]);
  *(bf16x4*)&xh[(size_t)i * 4] = h;
  *(bf16x4*)&xl[(size_t)i * 4] = l;
}

// ---------------- GEMM v3: m201-style phased schedule (unchanged from R6) ----------------
template <int EPI, bool SPLITA>
__global__ __launch_bounds__(512, 2) void gemmP(
    const bf16_t* __restrict__ Ah, const bf16_t* __restrict__ Al,
    const bf16_t* __restrict__ Bw,
    void* __restrict__ C0, void* __restrict__ C1,
    int M, int N, int K) {
  constexpr int BM = SPLITA ? 64 : 128;
  constexpr int MREP = SPLITA ? 2 : 4;
  constexpr int ABUF = BM * 64;
  constexpr int BBUF = 256 * 64;
  __shared__ __align__(16) bf16_t sA[3][ABUF];
  __shared__ __align__(16) bf16_t sA2[SPLITA ? 3 : 1][SPLITA ? ABUF : 8];
  __shared__ __align__(16) bf16_t sB[3][BBUF];

  const int tid = threadIdx.x;
  const int wid = tid >> 6, lane = tid & 63, lr = lane & 15, lg = lane >> 4;
  const int wr = wid >> 2, wc = wid & 3;
  const size_t Ks = (size_t)K;

  const int nwg = gridDim.x * gridDim.y;
  const int bid0 = blockIdx.y * gridDim.x + blockIdx.x;
  const int swz = (bid0 & 7) * (nwg >> 3) + (bid0 >> 3);
  const int bx = swz % gridDim.x, by = swz / gridDim.x;
  const size_t m0 = (size_t)by * BM, n0 = (size_t)bx * 256;
  const int nt = K / 64;

  f32x4 acc[MREP][4] = {};

  auto STAGEH = [&](int bi, int kt, int half) {
    const size_t ko = (size_t)kt * 64;
    if (half == 0) {
#pragma unroll
      for (int i = 0; i < BM / 64; i++) {
        const int t = i * 512 + tid;
        const int r = t >> 3;
        const int su = (t & 7) ^ (r & 7);
        const int lo = (i * 512 + wid * 64) * 8;
        gload16(Ah + (m0 + r) * Ks + ko + su * 8, (void*)&sA[bi][lo]);
        if constexpr (SPLITA) gload16(Al + (m0 + r) * Ks + ko + su * 8, (void*)&sA2[bi][lo]);
      }
      {
        const int r = tid >> 3;
        const int su = (tid & 7) ^ (r & 7);
        gload16(Bw + (n0 + r) * Ks + ko + su * 8, (void*)&sB[bi][(wid * 64) * 8]);
      }
    } else {
#pragma unroll
      for (int i = 1; i < 4; i++) {
        const int t = i * 512 + tid;
        const int r = t >> 3;
        const int su = (t & 7) ^ (r & 7);
        gload16(Bw + (n0 + r) * Ks + ko + su * 8, (void*)&sB[bi][(i * 512 + wid * 64) * 8]);
      }
    }
  };
  auto LDA = [&](const bf16_t* base, int m, int k) -> bf16x8 {
    const int row = wr * (BM / 2) + m * 16 + lr;
    const int u = (k * 4 + lg) ^ (lr & 7);
    return *(const bf16x8*)&base[row * 64 + u * 8];
  };
  auto LDB = [&](const bf16_t* base, int n, int k) -> bf16x8 {
    const int row = wc * 64 + n * 16 + lr;
    const int u = (k * 4 + lg) ^ (lr & 7);
    return *(const bf16x8*)&base[row * 64 + u * 8];
  };

  STAGEH(0, 0, 0); STAGEH(0, 0, 1);
  STAGEH(1, 1, 0); STAGEH(1, 1, 1);
  asm volatile("s_waitcnt vmcnt(6)" ::: "memory");
  __builtin_amdgcn_s_barrier();

  int bc = 0, bs = 2;
  for (int kt = 0; kt < nt; kt++) {
    const bool pf = (kt + 2 < nt);
    bf16x8 a[MREP][2], bfr[4][2];
#pragma unroll
    for (int m = 0; m < MREP; m++)
#pragma unroll
      for (int k = 0; k < 2; k++) a[m][k] = LDA(&sA[bc][0], m, k);
    if constexpr (SPLITA) {
#pragma unroll
      for (int n = 0; n < 4; n++)
#pragma unroll
        for (int k = 0; k < 2; k++) bfr[n][k] = LDB(&sB[bc][0], n, k);
    } else {
#pragma unroll
      for (int n = 0; n < 2; n++)
#pragma unroll
        for (int k = 0; k < 2; k++) bfr[n][k] = LDB(&sB[bc][0], n, k);
    }
    if (pf) STAGEH(bs, kt + 2, 0);
    __builtin_amdgcn_s_barrier();
    asm volatile("s_waitcnt lgkmcnt(0)" ::: "memory");
    __builtin_amdgcn_sched_barrier(0);
    __builtin_amdgcn_s_setprio(1);
    if constexpr (SPLITA) {
#pragma unroll
      for (int k = 0; k < 2; k++)
#pragma unroll
        for (int m = 0; m < MREP; m++)
#pragma unroll
          for (int n = 0; n < 4; n++) acc[m][n] = mfma16(a[m][k], bfr[n][k], acc[m][n]);
    } else {
#pragma unroll
      for (int k = 0; k < 2; k++)
#pragma unroll
        for (int m = 0; m < MREP; m++)
#pragma unroll
          for (int n = 0; n < 2; n++) acc[m][n] = mfma16(a[m][k], bfr[n][k], acc[m][n]);
    }
    __builtin_amdgcn_s_setprio(0);
    __builtin_amdgcn_s_barrier();
    if constexpr (SPLITA) {
#pragma unroll
      for (int m = 0; m < MREP; m++)
#pragma unroll
        for (int k = 0; k < 2; k++) a[m][k] = LDA(&sA2[bc][0], m, k);
    } else {
#pragma unroll
      for (int n = 0; n < 2; n++)
#pragma unroll
        for (int k = 0; k < 2; k++) bfr[n + 2][k] = LDB(&sB[bc][0], n + 2, k);
    }
    if (pf) STAGEH(bs, kt + 2, 1);
    if (kt + 1 < nt) {
      if (pf) asm volatile("s_waitcnt vmcnt(6)" ::: "memory");
      else    asm volatile("s_waitcnt vmcnt(0)" ::: "memory");
    }
    __builtin_amdgcn_s_barrier();
    asm volatile("s_waitcnt lgkmcnt(0)" ::: "memory");
    __builtin_amdgcn_sched_barrier(0);
    __builtin_amdgcn_s_setprio(1);
    if constexpr (SPLITA) {
#pragma unroll
      for (int k = 0; k < 2; k++)
#pragma unroll
        for (int m = 0; m < MREP; m++)
#pragma unroll
          for (int n = 0; n < 4; n++) acc[m][n] = mfma16(a[m][k], bfr[n][k], acc[m][n]);
    } else {
#pragma unroll
      for (int k = 0; k < 2; k++)
#pragma unroll
        for (int m = 0; m < MREP; m++)
#pragma unroll
          for (int n = 0; n < 2; n++) acc[m][n + 2] = mfma16(a[m][k], bfr[n + 2][k], acc[m][n + 2]);
    }
    __builtin_amdgcn_s_setprio(0);
    __builtin_amdgcn_s_barrier();
    bc = (bc + 1 == 3) ? 0 : bc + 1;
    bs = (bs + 1 == 3) ? 0 : bs + 1;
  }

  const int row0 = (int)m0 + wr * (BM / 2), colb = (int)n0 + wc * 64;
#pragma unroll
  for (int m = 0; m < MREP; m++)
#pragma unroll
    for (int n = 0; n < 4; n++)
#pragma unroll
      for (int j = 0; j < 4; j++) {
        const int r = row0 + m * 16 + lg * 4 + j;
        const int c = colb + n * 16 + lr;
        const float v = acc[m][n][j];
        if constexpr (EPI == 0) {
          bf16_t hi = (bf16_t)v;
          ((bf16_t*)C0)[(size_t)r * N + c] = hi;
          ((bf16_t*)C1)[(size_t)r * N + c] = (bf16_t)(v - (float)hi);
        } else if constexpr (EPI == 1) {
          const int bb = r >> 11, ss = r & 2047;
          ((bf16_t*)C0)[((size_t)bb * 2048 + c) * 2048 + ss] = (bf16_t)v;
        } else if constexpr (EPI == 2) {
          ((float*)C0)[(size_t)r * N + c] = v;
        } else {
          ((bf16_t*)C0)[(size_t)r * N + c] = (bf16_t)fmaxf(v, 0.f);
        }
      }
  (void)M;
}

// ---------------- flash attention v6: swapped QK^T, lane-local softmax ----------------
// 4 waves, q-tile 128 (2x16 rows/wave), KVBLK=64, K hi+lo LDS-staged (dbuf,
// vmcnt(8)). QK^T computed as mfma(K, Q): lane holds 16 k-values for ONE
// q-row (q = lr). Softmax: in-register tree + 2 shfls (xor 16/32); rescale
// is one scalar/lane. P redistributed via swizzled per-wave LDS (4 b64
// writes + 2 b128 reads per tile). PV swapped too: mfma(V^T, P) with V^T
// fragments direct from vT (shared across both q-tiles). Output (d=row,
// q=col) transposed once in an epilogue via swizzled LDS (reuses sKh).
__global__ __launch_bounds__(256, 2) void attn_k(
    const bf16_t* __restrict__ qh, const bf16_t* __restrict__ ql,
    const bf16_t* __restrict__ kh, const bf16_t* __restrict__ kl,
    const bf16_t* __restrict__ vT, bf16_t* __restrict__ out) {
  __shared__ __align__(16) bf16_t sKh[2 * 8192];   // 2 x [64][128]; epilogue scratch
  __shared__ __align__(16) bf16_t sKl[2 * 8192];
  __shared__ __align__(16) bf16_t plds[4][2048];   // per-wave P [2 tiles][16 q][64 kv]

  // XCD-aware remap: all 16 q-blocks of one bh land on the same XCD (fid%8).
  const int fid = blockIdx.y * 16 + blockIdx.x;
  const int qt = fid >> 5;
  const int bh = (fid & 7) * 4 + ((fid >> 3) & 3);
  const int b = bh >> 4, h = bh & 15;
  const int wv = threadIdx.x >> 6, lane = threadIdx.x & 63, lr = lane & 15, lg = lane >> 4;
  const size_t tok0 = (size_t)b * 2048 + qt * 128 + wv * 16;  // tile0; tile1 = +64
  bf16_t* pw = &plds[wv][0];

  auto STAGE = [&](int bufi, int kv0n) {
#pragma unroll
    for (int i = 0; i < 4; i++) {
      const int tt = wv * 4 + i;
      const int r = tt * 4 + (lane >> 4);
      const int ce = ((lane & 15) ^ (r & 7)) * 8;
      const size_t gofs = ((size_t)b * 2048 + kv0n + r) * 2048 + h * 128 + ce;
      gload16(kh + gofs, (void*)&sKh[bufi * 8192 + tt * 512]);
      gload16(kl + gofs, (void*)&sKl[bufi * 8192 + tt * 512]);
    }
  };

  bf16x8 qhf[2][4], qlf[2][4];
#pragma unroll
  for (int t = 0; t < 2; t++) {
    const bf16_t* qp = qh + (tok0 + t * 64 + lr) * 2048 + h * 128 + lg * 8;
    const bf16_t* qp2 = ql + (tok0 + t * 64 + lr) * 2048 + h * 128 + lg * 8;
#pragma unroll
    for (int ks = 0; ks < 4; ks++) {
      qhf[t][ks] = *(const bf16x8*)(qp + ks * 32);
      qlf[t][ks] = *(const bf16x8*)(qp2 + ks * 32);
    }
  }
  f32x4 oacc[2][8] = {};           // [tile][dt]: row d=dt*16+lg*4+j, col q=lr
  float mrun[2] = {-1e30f, -1e30f};
  float lrun[2] = {0.f, 0.f};
  const bf16_t* vbase = vT + ((size_t)b * 2048 + h * 128) * 2048;
  const float sc = 0.08838834764831845f;
  const int swz8 = 2 * (lr & 7);   // 8B-slot XOR swizzle for this lane's P/epi rows

  STAGE(0, 0);
  for (int c = 0; c < 32; c++) {
    const int kv0 = c * 64;
    if (c + 1 < 32) {
      STAGE((c + 1) & 1, kv0 + 64);
      asm volatile("s_waitcnt vmcnt(8)" ::: "memory");
    } else {
      asm volatile("s_waitcnt vmcnt(0)" ::: "memory");
    }
    __builtin_amdgcn_s_barrier();

    const int bufo = (c & 1) * 8192;
    // ---- swapped QK^T: s[t][nb] has row k=nb*16+lg*4+j, col q=lr ----
    f32x4 s[2][4] = {};
#pragma unroll
    for (int nb = 0; nb < 4; nb++) {
      const int rbase = bufo + (nb * 16 + lr) * 128;
#pragma unroll
      for (int ks = 0; ks < 4; ks++) {
        const int u = (((ks * 4 + lg) ^ (lr & 7)) * 8);
        bf16x8 kf = *(const bf16x8*)&sKh[rbase + u];
        bf16x8 kg = *(const bf16x8*)&sKl[rbase + u];
        s[0][nb] = mfma16(kf, qhf[0][ks], s[0][nb]);
        s[1][nb] = mfma16(kf, qhf[1][ks], s[1][nb]);
        s[0][nb] = mfma16(kf, qlf[0][ks], s[0][nb]);
        s[1][nb] = mfma16(kf, qlf[1][ks], s[1][nb]);
        s[0][nb] = mfma16(kg, qhf[0][ks], s[0][nb]);
        s[1][nb] = mfma16(kg, qhf[1][ks], s[1][nb]);
      }
    }

    // ---- per tile: lane-local softmax + P pack into swizzled LDS ----
    float resc[2];
#pragma unroll
    for (int t = 0; t < 2; t++) {
#pragma unroll
      for (int nb = 0; nb < 4; nb++) s[t][nb] *= sc;
      f32x4 m4 = s[t][0];
      m4 = __builtin_elementwise_max(m4, s[t][1]);
      m4 = __builtin_elementwise_max(m4, s[t][2]);
      m4 = __builtin_elementwise_max(m4, s[t][3]);
      float mx = fmaxf(fmaxf(m4[0], m4[1]), fmaxf(m4[2], m4[3]));
      mx = fmaxf(mx, __shfl_xor(mx, 16));
      mx = fmaxf(mx, __shfl_xor(mx, 32));
      const float mnew = fmaxf(mrun[t], mx);
      resc[t] = __expf(mrun[t] - mnew);
      mrun[t] = mnew;
      float ls = 0.f;
#pragma unroll
      for (int nb = 0; nb < 4; nb++) {
        bf16x4 pk;
#pragma unroll
        for (int j = 0; j < 4; j++) {
          const float p = __expf(s[t][nb][j] - mnew);
          ls += p;
          pk[j] = (bf16_t)p;
        }
        const int s8 = (4 * nb + lg) ^ swz8;           // 8B slot within row
        *(bf16x4*)&pw[t * 1024 + lr * 64 + s8 * 4] = pk;
      }
      ls += __shfl_xor(ls, 16);
      ls += __shfl_xor(ls, 32);
      lrun[t] = lrun[t] * resc[t] + ls;
    }
    // rescale O (scalar per lane: all regs share q=lr)
#pragma unroll
    for (int dt = 0; dt < 8; dt++) {
      oacc[0][dt] *= resc[0];
      oacc[1][dt] *= resc[1];
    }

    // ---- read P fragments (B operand: k=lg*8+e, col q=lr) ----
    bf16x8 pfr[2][2];
#pragma unroll
    for (int t = 0; t < 2; t++)
#pragma unroll
      for (int kc = 0; kc < 2; kc++) {
        const int se = (8 * kc + 2 * lg) ^ swz8;
        pfr[t][kc] = *(const bf16x8*)&pw[t * 1024 + lr * 64 + se * 4];
      }

    // ---- PV swapped: A = V^T (row d=dt*16+lr, k=kv), shared across tiles ----
    const bf16_t* vp = vbase + kv0 + lg * 8;
#pragma unroll
    for (int dt = 0; dt < 8; dt++) {
      const bf16_t* vr = vp + (size_t)(dt * 16 + lr) * 2048;
      bf16x8 v0 = *(const bf16x8*)(vr);
      bf16x8 v1 = *(const bf16x8*)(vr + 32);
      oacc[0][dt] = mfma16(v0, pfr[0][0], oacc[0][dt]);
      oacc[1][dt] = mfma16(v0, pfr[1][0], oacc[1][dt]);
      oacc[0][dt] = mfma16(v1, pfr[0][1], oacc[0][dt]);
      oacc[1][dt] = mfma16(v1, pfr[1][1], oacc[1][dt]);
    }
    asm volatile("" ::: "memory");
    __builtin_amdgcn_s_barrier();
  }

  // ---- epilogue: transpose (d=row,q=col) -> coalesced token-row stores ----
  asm volatile("s_waitcnt lgkmcnt(0)" ::: "memory");
#pragma unroll
  for (int t = 0; t < 2; t++) {
    bf16_t* ep = &sKh[wv * 4096 + t * 2048];    // [16 q][128 d] bf16
    const float inv = 1.f / lrun[t];
#pragma unroll
    for (int dt = 0; dt < 8; dt++) {
      bf16x4 pk;
#pragma unroll
      for (int j = 0; j < 4; j++) pk[j] = (bf16_t)(oacc[t][dt][j] * inv);
      const int s5 = (4 * dt + lg) ^ swz8;       // 32 8B-slots per row
      *(bf16x4*)&ep[lr * 128 + s5 * 4] = pk;
    }
  }
  asm volatile("s_waitcnt lgkmcnt(0)" ::: "memory");
  {
    const int q = lane >> 2, c4 = lane & 3;
    const int qs = 2 * (q & 7);
#pragma unroll
    for (int t = 0; t < 2; t++) {
      const bf16_t* ep = &sKh[wv * 4096 + t * 2048];
      bf16_t* orow = out + (tok0 + t * 64 + q) * 2048 + h * 128 + c4 * 32;
#pragma unroll
      for (int i = 0; i < 4; i++) {
        const int se = (c4 * 8 + 2 * i) ^ qs;
        bf16x8 vv = *(const bf16x8*)&ep[q * 128 + se * 4];
        *(bf16x8*)(orow + i * 8) = vv;
      }
    }
  }
}

// ---------------- fused residual + LayerNorm ----------------
__global__ __launch_bounds__(256) void ln_k(
    const float* __restrict__ X, const float* __restrict__ R,
    const float* __restrict__ G, const float* __restrict__ Bt,
    float* __restrict__ O32, bf16_t* __restrict__ O16) {
  const int t = blockIdx.x, tid = threadIdx.x;
  const float4* xp = (const float4*)(X + (size_t)t * 2048);
  const float4* rp = (const float4*)(R + (size_t)t * 2048);
  float4 v0 = xp[tid], w0 = rp[tid];
  float4 v1 = xp[tid + 256], w1 = rp[tid + 256];
  v0.x += w0.x; v0.y += w0.y; v0.z += w0.z; v0.w += w0.w;
  v1.x += w1.x; v1.y += w1.y; v1.z += w1.z; v1.w += w1.w;
  float sum = v0.x + v0.y + v0.z + v0.w + v1.x + v1.y + v1.z + v1.w;
  float sq = v0.x * v0.x + v0.y * v0.y + v0.z * v0.z + v0.w * v0.w +
             v1.x * v1.x + v1.y * v1.y + v1.z * v1.z + v1.w * v1.w;
  for (int d = 1; d < 64; d <<= 1) { sum += __shfl_xor(sum, d); sq += __shfl_xor(sq, d); }
  __shared__ float s1[4], s2[4];
  const int wv = tid >> 6, lane = tid & 63;
  if (lane == 0) { s1[wv] = sum; s2[wv] = sq; }
  __syncthreads();
  const float tot = s1[0] + s1[1] + s1[2] + s1[3];
  const float tsq = s2[0] + s2[1] + s2[2] + s2[3];
  const float mu = tot * (1.f / 2048.f);
  const float var = tsq * (1.f / 2048.f) - mu * mu;
  const float rs = 1.f / sqrtf(var + 1e-5f);
  const float4* gp = (const float4*)G;
  const float4* bp = (const float4*)Bt;
  float4 g0 = gp[tid], g1v = gp[tid + 256], b0 = bp[tid], b1v = bp[tid + 256];
  float4 o0, o1;
  o0.x = (v0.x - mu) * rs * g0.x + b0.x; o0.y = (v0.y - mu) * rs * g0.y + b0.y;
  o0.z = (v0.z - mu) * rs * g0.z + b0.z; o0.w = (v0.w - mu) * rs * g0.w + b0.w;
  o1.x = (v1.x - mu) * rs * g1v.x + b1v.x; o1.y = (v1.y - mu) * rs * g1v.y + b1v.y;
  o1.z = (v1.z - mu) * rs * g1v.z + b1v.z; o1.w = (v1.w - mu) * rs * g1v.w + b1v.w;
  ((float4*)(O32 + (size_t)t * 2048))[tid] = o0;
  ((float4*)(O32 + (size_t)t * 2048))[tid + 256] = o1;
  if (O16) {
    bf16x4 h0, h1;
    h0[0] = (bf16_t)o0.x; h0[1] = (bf16_t)o0.y; h0[2] = (bf16_t)o0.z; h0[3] = (bf16_t)o0.w;
    h1[0] = (bf16_t)o1.x; h1[1] = (bf16_t)o1.y; h1[2] = (bf16_t)o1.z; h1[3] = (bf16_t)o1.w;
    *(bf16x4*)&O16[(size_t)t * 2048 + tid * 4] = h0;
    *(bf16x4*)&O16[(size_t)t * 2048 + 1024 + tid * 4] = h1;
  }
}

// ---------------- launch ----------------
extern "C" void kernel_launch(void* const* d_in, const int* in_sizes, int n_in,
                              void* d_out, int out_size, void* d_ws, size_t ws_size,
                              hipStream_t stream) {
  const float* x  = (const float*)d_in[0];
  const float* Wq = (const float*)d_in[1];
  const float* Wk = (const float*)d_in[2];
  const float* Wv = (const float*)d_in[3];
  const float* Wo = (const float*)d_in[4];
  const float* W1 = (const float*)d_in[5];
  const float* W2 = (const float*)d_in[6];
  const float* g1 = (const float*)d_in[7];
  const float* b1 = (const float*)d_in[8];
  const float* g2 = (const float*)d_in[9];
  const float* b2 = (const float*)d_in[10];
  float* out = (float*)d_out;
  char* ws = (char*)d_ws;

  constexpr size_t SZB = (size_t)4096 * 2048 * 2;  // one bf16 [4096][2048] buffer
  bf16_t* xh = (bf16_t*)(ws + 0 * SZB);
  bf16_t* xl = (bf16_t*)(ws + 1 * SZB);
  bf16_t* qh = (bf16_t*)(ws + 2 * SZB);
  bf16_t* ql = (bf16_t*)(ws + 3 * SZB);
  bf16_t* kh = (bf16_t*)(ws + 4 * SZB);
  bf16_t* kl = (bf16_t*)(ws + 5 * SZB);
  bf16_t* vt = (bf16_t*)(ws + 6 * SZB);
  bf16_t* at = (bf16_t*)(ws + 7 * SZB);
  float* o32 = (float*)(ws + 8 * SZB);
  bf16_t* wt = (bf16_t*)(ws + 8 * SZB + (size_t)4096 * 2048 * 4);
  double* red = (double*)(ws + 8 * SZB + (size_t)4096 * 2048 * 4 + (size_t)8192 * 2048 * 2);
  double* sums = red + 8192;
  float* h1 = (float*)ws;       // over xh+xl
  bf16_t* h1b = qh;             // over qh
  bf16_t* f1 = kh;              // over kh,kl,vt,at
  float* g32 = o32;             // over o32
  (void)in_sizes; (void)n_in; (void)out_size; (void)ws_size;

  abssum_all<<<dim3(1024, 6), 256, 0, stream>>>(Wq, Wk, Wv, Wo, W1, W2, red);
  abssum_fin<<<6, 256, 0, stream>>>(red, sums);
  split_x_k<<<8192, 256, 0, stream>>>(x, xh, xl);

  ternarize_k<<<4096, 256, 0, stream>>>(Wq, wt, sums + 0, 4194304.0);
  gemmP<0, true><<<dim3(8, 64), 512, 0, stream>>>(xh, xl, wt, qh, ql, 4096, 2048, 2048);
  ternarize_k<<<4096, 256, 0, stream>>>(Wk, wt, sums + 1, 4194304.0);
  gemmP<0, true><<<dim3(8, 64), 512, 0, stream>>>(xh, xl, wt, kh, kl, 4096, 2048, 2048);
  ternarize_k<<<4096, 256, 0, stream>>>(Wv, wt, sums + 2, 4194304.0);
  gemmP<1, false><<<dim3(8, 32), 512, 0, stream>>>(xh, nullptr, wt, vt, nullptr, 4096, 2048, 2048);
  attn_k<<<dim3(16, 32), 256, 0, stream>>>(qh, ql, kh, kl, vt, at);
  ternarize_k<<<4096, 256, 0, stream>>>(Wo, wt, sums + 3, 4194304.0);
  gemmP<2, false><<<dim3(8, 32), 512, 0, stream>>>(at, nullptr, wt, o32, nullptr, 4096, 2048, 2048);
  ln_k<<<4096, 256, 0, stream>>>(x, o32, g1, b1, h1, h1b);
  ternarize_k<<<16384, 256, 0, stream>>>(W1, wt, sums + 4, 16777216.0);
  gemmP<3, false><<<dim3(32, 32), 512, 0, stream>>>(h1b, nullptr, wt, f1, nullptr, 4096, 8192, 2048);
  ternarize_k<<<16384, 256, 0, stream>>>(W2, wt, sums + 5, 16777216.0);
  gemmP<2, false><<<dim3(8, 32), 512, 0, stream>>>(f1, nullptr, wt, g32, nullptr, 4096, 2048, 8192);
  ln_k<<<4096, 256, 0, stream>>>(h1, g32, g2, b2, out, nullptr);
}